// Round 6
// baseline (1754.953 us; speedup 1.0000x reference)
//
#include <hip/hip_runtime.h>

#define NNET 32
#define NUNITS 2048
#define NEXC 1638
#define NINH 410

// Nontemporal 8B load of a float2 (weights are read exactly once).
__device__ __forceinline__ float2 nt2(const float2* p) {
    return __builtin_bit_cast(float2, __builtin_nontemporal_load((const double*)p));
}

// ---------------------------------------------------------------------------
// Jobs 1-4: acc[n,q] += sum_p W[n,p,q] * r[n,p]   (q contiguous within a row)
// Thread t owns float2 column c = qb*256+t (coalesced 512B/wave-instr).
// SIXTEEN named nt loads in flight per thread (128B).
// ---------------------------------------------------------------------------
__device__ __forceinline__ void col_matvec(const float* __restrict__ W,
                                           const float* __restrict__ r,
                                           float* __restrict__ acc,
                                           int rel_blk,
                                           int P, int Q, int QB, int PB, int PCH,
                                           int qoff, int vecoff) {
    int n   = rel_blk / (QB * PB);
    int rem = rel_blk % (QB * PB);
    int qb  = rem / PB;
    int pb  = rem % PB;

    int p0  = pb * PCH;
    int len = min(PCH, P - p0);
    int t   = threadIdx.x;

    __shared__ float s_r[256];            // PCH <= 205
    if (t < len) s_r[t] = r[n * NUNITS + vecoff + p0 + t];
    __syncthreads();

    int Q2 = Q >> 1;
    int c  = qb * 256 + t;
    if (c >= Q2) { __syncthreads(); return; }   // reconverge-safe (no later syncs)

    const float2* Wp  = (const float2*)(W + ((size_t)n * P + p0) * Q) + c;
    const size_t step = (size_t)Q2;

    float ax = 0.f, ay = 0.f;
    int p = 0;
    for (; p + 16 <= len; p += 16) {
        const float2* b = Wp + (size_t)p * step;
        float2 w0 = nt2(b +  0 * step), w1 = nt2(b +  1 * step);
        float2 w2 = nt2(b +  2 * step), w3 = nt2(b +  3 * step);
        float2 w4 = nt2(b +  4 * step), w5 = nt2(b +  5 * step);
        float2 w6 = nt2(b +  6 * step), w7 = nt2(b +  7 * step);
        float2 w8 = nt2(b +  8 * step), w9 = nt2(b +  9 * step);
        float2 wa = nt2(b + 10 * step), wb = nt2(b + 11 * step);
        float2 wc = nt2(b + 12 * step), wd = nt2(b + 13 * step);
        float2 we = nt2(b + 14 * step), wf = nt2(b + 15 * step);
        ax += w0.x*s_r[p+0] + w1.x*s_r[p+1] + w2.x*s_r[p+2] + w3.x*s_r[p+3]
            + w4.x*s_r[p+4] + w5.x*s_r[p+5] + w6.x*s_r[p+6] + w7.x*s_r[p+7]
            + w8.x*s_r[p+8] + w9.x*s_r[p+9] + wa.x*s_r[p+10]+ wb.x*s_r[p+11]
            + wc.x*s_r[p+12]+ wd.x*s_r[p+13]+ we.x*s_r[p+14]+ wf.x*s_r[p+15];
        ay += w0.y*s_r[p+0] + w1.y*s_r[p+1] + w2.y*s_r[p+2] + w3.y*s_r[p+3]
            + w4.y*s_r[p+4] + w5.y*s_r[p+5] + w6.y*s_r[p+6] + w7.y*s_r[p+7]
            + w8.y*s_r[p+8] + w9.y*s_r[p+9] + wa.y*s_r[p+10]+ wb.y*s_r[p+11]
            + wc.y*s_r[p+12]+ wd.y*s_r[p+13]+ we.y*s_r[p+14]+ wf.y*s_r[p+15];
    }
    for (; p < len; ++p) {
        float2 w = nt2(Wp + (size_t)p * step);
        ax += w.x * s_r[p];
        ay += w.y * s_r[p];
    }

    atomicAdd(&acc[n * NUNITS + qoff + 2 * c],     ax);
    atomicAdd(&acc[n * NUNITS + qoff + 2 * c + 1], ay);
}

// ---------------------------------------------------------------------------
// Job 5: inter_inh[i,a] = sum_{j,b} W_inter[i,j,a,b] * r[i, NEXC+b]
// Block = (i, j, half-plane): contiguous 336KB chunk. Wave-per-row dots,
// FOUR rows in flight (13-16 nt loads), interleaved shfl reduce.
// ---------------------------------------------------------------------------
__device__ __forceinline__ float row_dot(const float2* __restrict__ row2,
                                         const float* __restrict__ s_ri, int lane) {
    // 205 float2s: lane, lane+64, lane+128 always valid; lane+192 iff lane<13
    float2 w0 = nt2(row2 + lane);
    float2 w1 = nt2(row2 + lane + 64);
    float2 w2 = nt2(row2 + lane + 128);
    float s = w0.x * s_ri[2*lane]       + w0.y * s_ri[2*lane + 1]
            + w1.x * s_ri[2*lane + 128] + w1.y * s_ri[2*lane + 129]
            + w2.x * s_ri[2*lane + 256] + w2.y * s_ri[2*lane + 257];
    if (lane < 13) {
        float2 w3 = nt2(row2 + lane + 192);
        s += w3.x * s_ri[2*lane + 384] + w3.y * s_ri[2*lane + 385];
    }
    return s;
}

__device__ __forceinline__ void inter_ij(const float* __restrict__ Wint,
                                         const float* __restrict__ r,
                                         float* __restrict__ acc,
                                         int rel_blk) {
    int i    = rel_blk >> 6;          // /64
    int j    = (rel_blk >> 1) & 31;
    int half = rel_blk & 1;

    __shared__ float s_ri[NINH];
    for (int t = threadIdx.x; t < NINH; t += 256)
        s_ri[t] = r[i * NUNITS + NEXC + t];   // einsum 'ijab,ib->ia': r of network i
    __syncthreads();

    int wave = threadIdx.x >> 6;
    int lane = threadIdx.x & 63;

    const float* plane = Wint + (size_t)(i * NNET + j) * NINH * NINH;
    float* outp = acc + i * NUNITS + NEXC;
    int a0 = half * 205;
    int a1 = a0 + 205;                 // 410 = 2*205

    int a = a0 + wave;
    for (; a + 12 < a1; a += 16) {     // rows a, a+4, a+8, a+12 together
        float s0 = row_dot((const float2*)(plane + (size_t)(a     ) * NINH), s_ri, lane);
        float s1 = row_dot((const float2*)(plane + (size_t)(a +  4) * NINH), s_ri, lane);
        float s2 = row_dot((const float2*)(plane + (size_t)(a +  8) * NINH), s_ri, lane);
        float s3 = row_dot((const float2*)(plane + (size_t)(a + 12) * NINH), s_ri, lane);
        for (int off = 32; off; off >>= 1) {
            s0 += __shfl_down(s0, off, 64);
            s1 += __shfl_down(s1, off, 64);
            s2 += __shfl_down(s2, off, 64);
            s3 += __shfl_down(s3, off, 64);
        }
        if (lane == 0) {
            atomicAdd(&outp[a],      s0);
            atomicAdd(&outp[a +  4], s1);
            atomicAdd(&outp[a +  8], s2);
            atomicAdd(&outp[a + 12], s3);
        }
    }
    for (; a < a1; a += 4) {
        float s = row_dot((const float2*)(plane + (size_t)a * NINH), s_ri, lane);
        for (int off = 32; off; off >>= 1)
            s += __shfl_down(s, off, 64);
        if (lane == 0)
            atomicAdd(&outp[a], s);
    }
}

// ---------------------------------------------------------------------------
// Fused kernel, templated on repeat count. REPS=1 is the real pass; REPS=2 is
// a self-probe (same blocks redo their work) whose ~2x duration surfaces it in
// rocprof's top-5 with counters for exactly this access pattern.
// Flat grid, 3648 blocks:
//   [0,1024)     W_ee:   QB=4, PB=8
//   [1024,1280)  W_ie:   QB=4, PB=2
//   [1280,1536)  W_ei:   QB=1, PB=8
//   [1536,1600)  W_ii:   QB=1, PB=2
//   [1600,3648)  W_inter: 32*32*2 contiguous half-planes
// ---------------------------------------------------------------------------
template<int REPS>
__global__ __launch_bounds__(256) void fused_matvec(
    const float* __restrict__ Wee, const float* __restrict__ Wei,
    const float* __restrict__ Wie, const float* __restrict__ Wii,
    const float* __restrict__ Wint,
    const float* __restrict__ r, float* __restrict__ acc) {
    int blk = blockIdx.x;
    for (int rep = 0; rep < REPS; ++rep) {
        if (blk < 1024) {
            col_matvec(Wee, r, acc, blk,        1638, 1638, 4, 8, 205, 0,    0);
        } else if (blk < 1280) {
            col_matvec(Wie, r, acc, blk - 1024,  410, 1638, 4, 2, 205, 0,    NEXC);
        } else if (blk < 1536) {
            col_matvec(Wei, r, acc, blk - 1280, 1638,  410, 1, 8, 205, NEXC, 0);
        } else if (blk < 1600) {
            col_matvec(Wii, r, acc, blk - 1536,  410,  410, 1, 2, 205, NEXC, NEXC);
        } else {
            inter_ij(Wint, r, acc, blk - 1600);
        }
        if (REPS > 1) __syncthreads();
    }
}

// ---------------------------------------------------------------------------
// Finalize: r_new = 0.9*r + 0.1*relu(acc + unit_input)
// ---------------------------------------------------------------------------
__global__ __launch_bounds__(256) void finalize_kernel(
    const float* __restrict__ r, const float* __restrict__ uin,
    const float* __restrict__ acc, float* __restrict__ out) {
    int idx = blockIdx.x * 256 + threadIdx.x;
    if (idx < NNET * NUNITS) {
        float total = acc[idx] + uin[idx];
        float phi = fmaxf(total, 0.f);
        out[idx] = 0.9f * r[idx] + 0.1f * phi;
    }
}

extern "C" void kernel_launch(void* const* d_in, const int* in_sizes, int n_in,
                              void* d_out, int out_size, void* d_ws, size_t ws_size,
                              hipStream_t stream) {
    const float* unit_input = (const float*)d_in[0];
    const float* r          = (const float*)d_in[1];
    const float* W_ee       = (const float*)d_in[2];
    const float* W_ei       = (const float*)d_in[3];
    const float* W_ie       = (const float*)d_in[4];
    const float* W_ii       = (const float*)d_in[5];
    const float* W_inter    = (const float*)d_in[6];
    float* out  = (float*)d_out;
    float* acc  = (float*)d_ws;                          // 256 KB
    float* acc2 = (float*)((char*)d_ws + (1 << 20));     // probe scratch

    hipMemsetAsync(acc, 0, NNET * NUNITS * sizeof(float), stream);

    fused_matvec<1><<<3648, 256, 0, stream>>>(W_ee, W_ei, W_ie, W_ii, W_inter, r, acc);

    finalize_kernel<<<(NNET * NUNITS + 255) / 256, 256, 0, stream>>>(r, unit_input, acc, out);

    // Self-probe: 2x work into scratch; surfaces this access pattern in rocprof top-5.
    fused_matvec<2><<<3648, 256, 0, stream>>>(W_ee, W_ei, W_ie, W_ii, W_inter, r, acc2);
}

// Round 7
// 1237.254 us; speedup vs baseline: 1.4184x; 1.4184x over previous
//
#include <hip/hip_runtime.h>

#define NNET 32
#define NUNITS 2048
#define NEXC 1638
#define NINH 410

// 16B / 8B nontemporal loads with an honest 8-byte alignment contract
// (rows of Q=1638/410 floats start at 8B-aligned, not always 16B-aligned,
// addresses; gfx950 global loads support dword-aligned dwordx4).
typedef float f4 __attribute__((ext_vector_type(4), aligned(8)));
typedef float f2 __attribute__((ext_vector_type(2), aligned(8)));

__device__ __forceinline__ f4 nt4(const float* p) {
    return __builtin_nontemporal_load((const f4*)p);
}
__device__ __forceinline__ f2 nt2f(const float* p) {
    return __builtin_nontemporal_load((const f2*)p);
}

// ---------------------------------------------------------------------------
// Jobs 1-4: acc[n,q] += sum_p W[n,p,q] * r[n,p]   (q contiguous within a row)
// Thread t owns float4 column-slot c = qb*256+t (floats 4c..4c+3): coalesced
// 1KB/wave-instr. EIGHT named 16B nt loads in flight per thread (128B).
// Q % 4 == 2 for both 1638 and 410: slot nf4 is a float2 tail.
// ---------------------------------------------------------------------------
__device__ __forceinline__ void col_matvec(const float* __restrict__ W,
                                           const float* __restrict__ r,
                                           float* __restrict__ acc,
                                           int rel_blk,
                                           int P, int Q, int QB, int PB, int PCH,
                                           int qoff, int vecoff) {
    int n   = rel_blk / (QB * PB);
    int rem = rel_blk % (QB * PB);
    int qb  = rem / PB;
    int pb  = rem % PB;

    int p0  = pb * PCH;
    int len = min(PCH, P - p0);
    int t   = threadIdx.x;

    __shared__ float s_r[256];            // PCH <= 205
    if (t < len) s_r[t] = r[n * NUNITS + vecoff + p0 + t];
    __syncthreads();

    int nf4  = Q >> 2;                    // 409 (Q=1638) or 102 (Q=410)
    int slot = qb * 256 + t;
    const float* base = W + ((size_t)n * P + p0) * Q;

    if (slot < nf4) {
        const float* Wp = base + 4 * slot;
        float ax = 0.f, ay = 0.f, az = 0.f, aw = 0.f;
        int p = 0;
        for (; p + 8 <= len; p += 8) {
            const float* b = Wp + (size_t)p * Q;
            f4 w0 = nt4(b + 0 * (size_t)Q), w1 = nt4(b + 1 * (size_t)Q);
            f4 w2 = nt4(b + 2 * (size_t)Q), w3 = nt4(b + 3 * (size_t)Q);
            f4 w4 = nt4(b + 4 * (size_t)Q), w5 = nt4(b + 5 * (size_t)Q);
            f4 w6 = nt4(b + 6 * (size_t)Q), w7 = nt4(b + 7 * (size_t)Q);
            float r0 = s_r[p+0], r1 = s_r[p+1], r2 = s_r[p+2], r3 = s_r[p+3];
            float r4 = s_r[p+4], r5 = s_r[p+5], r6 = s_r[p+6], r7 = s_r[p+7];
            ax += w0.x*r0 + w1.x*r1 + w2.x*r2 + w3.x*r3
                + w4.x*r4 + w5.x*r5 + w6.x*r6 + w7.x*r7;
            ay += w0.y*r0 + w1.y*r1 + w2.y*r2 + w3.y*r3
                + w4.y*r4 + w5.y*r5 + w6.y*r6 + w7.y*r7;
            az += w0.z*r0 + w1.z*r1 + w2.z*r2 + w3.z*r3
                + w4.z*r4 + w5.z*r5 + w6.z*r6 + w7.z*r7;
            aw += w0.w*r0 + w1.w*r1 + w2.w*r2 + w3.w*r3
                + w4.w*r4 + w5.w*r5 + w6.w*r6 + w7.w*r7;
        }
        for (; p < len; ++p) {
            f4 w = nt4(Wp + (size_t)p * Q);
            float rp = s_r[p];
            ax += w.x * rp; ay += w.y * rp; az += w.z * rp; aw += w.w * rp;
        }
        float* o = acc + n * NUNITS + qoff + 4 * slot;
        atomicAdd(o + 0, ax);
        atomicAdd(o + 1, ay);
        atomicAdd(o + 2, az);
        atomicAdd(o + 3, aw);
    } else if (slot == nf4) {
        // float2 tail: columns Q-2, Q-1
        const float* Wp = base + (Q - 2);
        float ax = 0.f, ay = 0.f;
        int p = 0;
        for (; p + 8 <= len; p += 8) {
            const float* b = Wp + (size_t)p * Q;
            f2 w0 = nt2f(b + 0 * (size_t)Q), w1 = nt2f(b + 1 * (size_t)Q);
            f2 w2 = nt2f(b + 2 * (size_t)Q), w3 = nt2f(b + 3 * (size_t)Q);
            f2 w4 = nt2f(b + 4 * (size_t)Q), w5 = nt2f(b + 5 * (size_t)Q);
            f2 w6 = nt2f(b + 6 * (size_t)Q), w7 = nt2f(b + 7 * (size_t)Q);
            ax += w0.x*s_r[p+0] + w1.x*s_r[p+1] + w2.x*s_r[p+2] + w3.x*s_r[p+3]
                + w4.x*s_r[p+4] + w5.x*s_r[p+5] + w6.x*s_r[p+6] + w7.x*s_r[p+7];
            ay += w0.y*s_r[p+0] + w1.y*s_r[p+1] + w2.y*s_r[p+2] + w3.y*s_r[p+3]
                + w4.y*s_r[p+4] + w5.y*s_r[p+5] + w6.y*s_r[p+6] + w7.y*s_r[p+7];
        }
        for (; p < len; ++p) {
            f2 w = nt2f(Wp + (size_t)p * Q);
            ax += w.x * s_r[p];
            ay += w.y * s_r[p];
        }
        float* o = acc + n * NUNITS + qoff + (Q - 2);
        atomicAdd(o + 0, ax);
        atomicAdd(o + 1, ay);
    }
}

// ---------------------------------------------------------------------------
// Job 5: inter_inh[i,a] = sum_{j,b} W_inter[i,j,a,b] * r[i, NEXC+b]
// Block = (i, j, half-plane): contiguous 336KB chunk. Wave-per-row float4
// dots (102 f4 + 1 f2 tail per 410-float row), FOUR rows in flight.
// ---------------------------------------------------------------------------
__device__ __forceinline__ float row_dot4(const float* __restrict__ row,
                                          const float* __restrict__ s_ri, int lane) {
    f4 w0 = nt4(row + 4 * lane);                    // floats 0..255
    int b0 = 4 * lane;
    float s = w0.x*s_ri[b0] + w0.y*s_ri[b0+1] + w0.z*s_ri[b0+2] + w0.w*s_ri[b0+3];
    if (lane < 38) {                                // floats 256..407
        f4 w1 = nt4(row + 256 + 4 * lane);
        int b1 = 256 + 4 * lane;
        s += w1.x*s_ri[b1] + w1.y*s_ri[b1+1] + w1.z*s_ri[b1+2] + w1.w*s_ri[b1+3];
    } else if (lane == 38) {                        // tail floats 408,409
        f2 w1 = nt2f(row + 408);
        s += w1.x*s_ri[408] + w1.y*s_ri[409];
    }
    return s;
}

__device__ __forceinline__ void inter_ij(const float* __restrict__ Wint,
                                         const float* __restrict__ r,
                                         float* __restrict__ acc,
                                         int rel_blk) {
    int i    = rel_blk >> 6;          // /64
    int j    = (rel_blk >> 1) & 31;
    int half = rel_blk & 1;

    __shared__ float s_ri[NINH];
    for (int t = threadIdx.x; t < NINH; t += 256)
        s_ri[t] = r[i * NUNITS + NEXC + t];   // einsum 'ijab,ib->ia': r of network i
    __syncthreads();

    int wave = threadIdx.x >> 6;
    int lane = threadIdx.x & 63;

    const float* plane = Wint + (size_t)(i * NNET + j) * NINH * NINH;
    float* outp = acc + i * NUNITS + NEXC;
    int a0 = half * 205;
    int a1 = a0 + 205;                 // 410 = 2*205

    int a = a0 + wave;
    for (; a + 12 < a1; a += 16) {     // rows a, a+4, a+8, a+12 in flight
        float s0 = row_dot4(plane + (size_t)(a     ) * NINH, s_ri, lane);
        float s1 = row_dot4(plane + (size_t)(a +  4) * NINH, s_ri, lane);
        float s2 = row_dot4(plane + (size_t)(a +  8) * NINH, s_ri, lane);
        float s3 = row_dot4(plane + (size_t)(a + 12) * NINH, s_ri, lane);
        for (int off = 32; off; off >>= 1) {
            s0 += __shfl_down(s0, off, 64);
            s1 += __shfl_down(s1, off, 64);
            s2 += __shfl_down(s2, off, 64);
            s3 += __shfl_down(s3, off, 64);
        }
        if (lane == 0) {
            atomicAdd(&outp[a],      s0);
            atomicAdd(&outp[a +  4], s1);
            atomicAdd(&outp[a +  8], s2);
            atomicAdd(&outp[a + 12], s3);
        }
    }
    for (; a < a1; a += 4) {
        float s = row_dot4(plane + (size_t)a * NINH, s_ri, lane);
        for (int off = 32; off; off >>= 1)
            s += __shfl_down(s, off, 64);
        if (lane == 0)
            atomicAdd(&outp[a], s);
    }
}

// ---------------------------------------------------------------------------
// Fused kernel. Flat grid, 3008 blocks:
//   [0,512)     W_ee:   QB=2, PB=8
//   [512,640)   W_ie:   QB=2, PB=2
//   [640,896)   W_ei:   QB=1, PB=8
//   [896,960)   W_ii:   QB=1, PB=2
//   [960,3008)  W_inter: 32*32*2 contiguous half-planes
// ---------------------------------------------------------------------------
__global__ __launch_bounds__(256) void fused_matvec(
    const float* __restrict__ Wee, const float* __restrict__ Wei,
    const float* __restrict__ Wie, const float* __restrict__ Wii,
    const float* __restrict__ Wint,
    const float* __restrict__ r, float* __restrict__ acc) {
    int blk = blockIdx.x;
    if (blk < 512) {
        col_matvec(Wee, r, acc, blk,       1638, 1638, 2, 8, 205, 0,    0);
    } else if (blk < 640) {
        col_matvec(Wie, r, acc, blk - 512,  410, 1638, 2, 2, 205, 0,    NEXC);
    } else if (blk < 896) {
        col_matvec(Wei, r, acc, blk - 640, 1638,  410, 1, 8, 205, NEXC, 0);
    } else if (blk < 960) {
        col_matvec(Wii, r, acc, blk - 896,  410,  410, 1, 2, 205, NEXC, NEXC);
    } else {
        inter_ij(Wint, r, acc, blk - 960);
    }
}

// ---------------------------------------------------------------------------
// Finalize: r_new = 0.9*r + 0.1*relu(acc + unit_input)
// ---------------------------------------------------------------------------
__global__ __launch_bounds__(256) void finalize_kernel(
    const float* __restrict__ r, const float* __restrict__ uin,
    const float* __restrict__ acc, float* __restrict__ out) {
    int idx = blockIdx.x * 256 + threadIdx.x;
    if (idx < NNET * NUNITS) {
        float total = acc[idx] + uin[idx];
        float phi = fmaxf(total, 0.f);
        out[idx] = 0.9f * r[idx] + 0.1f * phi;
    }
}

extern "C" void kernel_launch(void* const* d_in, const int* in_sizes, int n_in,
                              void* d_out, int out_size, void* d_ws, size_t ws_size,
                              hipStream_t stream) {
    const float* unit_input = (const float*)d_in[0];
    const float* r          = (const float*)d_in[1];
    const float* W_ee       = (const float*)d_in[2];
    const float* W_ei       = (const float*)d_in[3];
    const float* W_ie       = (const float*)d_in[4];
    const float* W_ii       = (const float*)d_in[5];
    const float* W_inter    = (const float*)d_in[6];
    float* out = (float*)d_out;
    float* acc = (float*)d_ws;  // 32*2048 floats = 256 KB

    hipMemsetAsync(acc, 0, NNET * NUNITS * sizeof(float), stream);

    fused_matvec<<<3008, 256, 0, stream>>>(W_ee, W_ei, W_ie, W_ii, W_inter, r, acc);

    finalize_kernel<<<(NNET * NUNITS + 255) / 256, 256, 0, stream>>>(r, unit_input, acc, out);
}